// Round 3
// baseline (543.819 us; speedup 1.0000x reference)
//
#include <hip/hip_runtime.h>
#include <math.h>

// GDecode: logits[m,v] = sum_{h,k} phi[m, h*64+k] * psi[perm[h,v], k]; out = softmax_v(logits)
// M=2048 (B*N), C=512 (G*K), V=32000.
// Fast path: prep kernels pre-convert phi (hi/lo f16 Dekker) and pre-gather psi (f16) into
// LDS-image tile layouts in workspace; gemm stages via double-buffered global_load_lds with
// DEPTH-2 COUNTED vmcnt pipeline (T3+T4: wait vmcnt(6), never 0 in steady state, raw
// s_barrier — no compiler-inserted vmcnt(0) drain), XCD-chunked block swizzle so each XCD's
// L2 holds one 4 MB BWS chunk. Numerics identical to the verified kernel (same hi/lo split,
// same RNE psi cast, same MFMA accumulation order).

#define M_ROWS 2048
#define V_DIM  32000
#define C_DIM  512
#define G_DIM  8
#define K_DIM  64
#define BM     128
#define BV     128
#define BK     32
#define NVBLK  (V_DIM / BV)   // 250
#define NMT    (M_ROWS / BM)  // 16
#define NKT    (C_DIM / BK)   // 16
#define NSEG   25             // combine1 vb segments
#define SEGV   (NVBLK / NSEG) // 10
#define LDSBUF 12288          // f16 elems per pipeline buffer: Ah(4096) | Al(4096) | B(4096)
#define LDS_ROW 40            // fallback-path pad (old kernel)

typedef _Float16 f16x8 __attribute__((ext_vector_type(8)));
typedef _Float16 f16x4 __attribute__((ext_vector_type(4)));
typedef float    f32x4 __attribute__((ext_vector_type(4)));

// ------------------------------------------------------------------
// fast path
// ------------------------------------------------------------------

__device__ __forceinline__ void gl_lds16(const void* g, void* l) {
  __builtin_amdgcn_global_load_lds(
      (const __attribute__((address_space(1))) unsigned int*)g,
      (__attribute__((address_space(3))) unsigned int*)l, 16, 0, 0);
}

// AWS layout: [mt 16][it 16][half 2][kq 4][row 128][8 f16]  (tile = 8 KB, half: 0=hi 1=lo)
__global__ __launch_bounds__(256) void gdecode_prep_phi(
    const float* __restrict__ phi, _Float16* __restrict__ aws)
{
  const int ga   = blockIdx.x * 256 + threadIdx.x;  // [0, 16*16*2*512)
  const int g    = ga & 511;
  const int half = (ga >> 9) & 1;
  const int tile = ga >> 10;                        // mt*16 + it
  const int kq = g >> 7, r = g & 127;
  const int m  = (tile >> 4) * BM + r;
  const int k  = (tile & 15) * BK + kq * 8;
  const float4 x0 = *(const float4*)(phi + (size_t)m * C_DIM + k);
  const float4 x1 = *(const float4*)(phi + (size_t)m * C_DIM + k + 4);
  const float xs[8] = {x0.x, x0.y, x0.z, x0.w, x1.x, x1.y, x1.z, x1.w};
  f16x8 o;
  #pragma unroll
  for (int j = 0; j < 8; ++j) {
    _Float16 hi = (_Float16)xs[j];
    o[j] = half ? (_Float16)(xs[j] - (float)hi) : hi;
  }
  *(f16x8*)(aws + (size_t)ga * 8) = o;
}

// BWS layout: [it 16][vb 250][kq 4][row 128][8 f16]  (tile = 8 KB; it -> h=it>>1, kin=(it&1)*32)
__global__ __launch_bounds__(256) void gdecode_prep_psi(
    const float* __restrict__ psi, const int* __restrict__ perm, const int pstride,
    _Float16* __restrict__ bws)
{
  const int gb   = blockIdx.x * 256 + threadIdx.x;  // [0, 16*250*512)
  const int g    = gb & 511;
  const int tile = gb >> 9;                         // it*250 + vb
  const int it = tile / 250;
  const int vb = tile - it * 250;
  const int kq = g >> 7, r = g & 127;
  const int h   = it >> 1;
  const int kin = (it & 1) * 32 + kq * 8;
  const int v   = vb * BV + r;
  const int pr  = perm[(size_t)(h * V_DIM + v) * pstride];
  const float4 x0 = *(const float4*)(psi + (size_t)pr * K_DIM + kin);
  const float4 x1 = *(const float4*)(psi + (size_t)pr * K_DIM + kin + 4);
  f16x8 o = {(_Float16)x0.x, (_Float16)x0.y, (_Float16)x0.z, (_Float16)x0.w,
             (_Float16)x1.x, (_Float16)x1.y, (_Float16)x1.z, (_Float16)x1.w};
  *(f16x8*)(bws + (size_t)gb * 8) = o;
}

__global__ __launch_bounds__(256, 4) void gdecode_gemm2(
    const _Float16* __restrict__ aws, const _Float16* __restrict__ bws,
    float* __restrict__ out, float* __restrict__ smax, float* __restrict__ ssum)
{
  __shared__ __align__(16) _Float16 lds[2 * LDSBUF];   // 48 KiB: double-buffered Ah|Al|B

  // XCD-chunked swizzle: grid = 4096, b%8 = XCD, each XCD owns vb chunk [xcd*32, +32)
  // (4 MB of BWS = one L2), sweeps mt with vb-inner order for A-tile sharing.
  const int b   = blockIdx.x;
  const int xcd = b & 7;
  const int i   = b >> 3;            // 0..511
  const int mt  = i >> 5;            // 0..15  (vb-inner, mt-outer within XCD)
  const int vb  = xcd * 32 + (i & 31);
  if (vb >= NVBLK) return;           // 96 pad blocks (return before any barrier)

  const int vbase = vb * BV;
  const int mbase = mt * BM;

  const int t    = threadIdx.x;
  const int wid  = t >> 6;
  const int lane = t & 63;
  const int wm   = wid & 1;
  const int wv   = wid >> 1;
  const int lrow = lane & 15;
  const int quad = lane >> 4;

  const _Float16* gA = aws + (size_t)mt * NKT * 2 * 4096;
  const _Float16* gB = bws + (size_t)vb * 4096;

  // stage K-step `it` into pipeline buffer dst (6 x 16B-per-lane DMA, linear layout)
  auto STAGE = [&](int it, _Float16* dst) {
    const _Float16* ga = gA + (size_t)it * 2 * 4096;        // hi tile; lo at +4096
    const _Float16* gb = gB + (size_t)it * NVBLK * 4096;
    gl_lds16(ga + (size_t)t * 8,          dst + t * 8);
    gl_lds16(ga + 2048 + (size_t)t * 8,   dst + 2048 + t * 8);
    gl_lds16(ga + 4096 + (size_t)t * 8,   dst + 4096 + t * 8);
    gl_lds16(ga + 6144 + (size_t)t * 8,   dst + 6144 + t * 8);
    gl_lds16(gb + (size_t)t * 8,          dst + 8192 + t * 8);
    gl_lds16(gb + 2048 + (size_t)t * 8,   dst + 8192 + 2048 + t * 8);
  };

  f32x4 acc[4][4] = {};

  // depth-2 prefetch: 12 loads in flight
  STAGE(0, lds);
  STAGE(1, lds + LDSBUF);

  #pragma unroll 2
  for (int it = 0; it < 16; ++it) {
    _Float16* cur = lds + (it & 1) * LDSBUF;

    // wait ONLY tile `it`'s 6 loads (6 newer stay in flight); drain fully on last tile
    if (it < 15) asm volatile("s_waitcnt vmcnt(6)" ::: "memory");
    else         asm volatile("s_waitcnt vmcnt(0)" ::: "memory");
    __builtin_amdgcn_s_barrier();          // tile `it` visible to all waves

    const _Float16* sAh = cur;
    const _Float16* sAl = cur + 4096;
    const _Float16* sB  = cur + 8192;

    f16x8 ah[4], al[4], bf[4];
    #pragma unroll
    for (int k = 0; k < 4; ++k) {
      const int ra = quad * 1024 + (wm * 64 + k * 16 + lrow) * 8;
      const int rb = quad * 1024 + (wv * 64 + k * 16 + lrow) * 8;
      ah[k] = *(const f16x8*)(sAh + ra);
      al[k] = *(const f16x8*)(sAl + ra);
      bf[k] = *(const f16x8*)(sB + rb);
    }
    #pragma unroll
    for (int k = 0; k < 4; ++k) {
      #pragma unroll
      for (int j = 0; j < 4; ++j) {
        acc[k][j] = __builtin_amdgcn_mfma_f32_16x16x32_f16(ah[k], bf[j], acc[k][j], 0, 0, 0);
        acc[k][j] = __builtin_amdgcn_mfma_f32_16x16x32_f16(al[k], bf[j], acc[k][j], 0, 0, 0);
      }
    }
    // all this wave's LDS reads done; fence so nothing crosses the barrier, then all waves
    // have finished reading `cur` -> safe to overwrite with tile it+2 (loads span barrier)
    asm volatile("s_waitcnt lgkmcnt(0)" ::: "memory");
    __builtin_amdgcn_s_barrier();
    if (it < 14) STAGE(it + 2, cur);
  }

  // ---- epilogue: per-(row, vtile) stats + raw logit store (nontemporal) ----
  float* redmax = (float*)lds;        // [BM][2]
  float* redsum = redmax + 2 * BM;    // [BM][2]
  const int rowb = wm * 64;

  #pragma unroll
  for (int k = 0; k < 4; ++k) {
    #pragma unroll
    for (int r = 0; r < 4; ++r) {
      float v = fmaxf(fmaxf(acc[k][0][r], acc[k][1][r]),
                      fmaxf(acc[k][2][r], acc[k][3][r]));
      v = fmaxf(v, __shfl_xor(v, 1));
      v = fmaxf(v, __shfl_xor(v, 2));
      v = fmaxf(v, __shfl_xor(v, 4));
      v = fmaxf(v, __shfl_xor(v, 8));
      if (lrow == 0) redmax[(rowb + k * 16 + quad * 4 + r) * 2 + wv] = v;
    }
  }
  __syncthreads();
  float gmx[4][4];
  #pragma unroll
  for (int k = 0; k < 4; ++k) {
    #pragma unroll
    for (int r = 0; r < 4; ++r) {
      int row = rowb + k * 16 + quad * 4 + r;
      gmx[k][r] = fmaxf(redmax[row * 2], redmax[row * 2 + 1]);
    }
  }
  #pragma unroll
  for (int k = 0; k < 4; ++k) {
    #pragma unroll
    for (int r = 0; r < 4; ++r) {
      float s = __expf(acc[k][0][r] - gmx[k][r]) + __expf(acc[k][1][r] - gmx[k][r])
              + __expf(acc[k][2][r] - gmx[k][r]) + __expf(acc[k][3][r] - gmx[k][r]);
      s += __shfl_xor(s, 1);
      s += __shfl_xor(s, 2);
      s += __shfl_xor(s, 4);
      s += __shfl_xor(s, 8);
      if (lrow == 0) redsum[(rowb + k * 16 + quad * 4 + r) * 2 + wv] = s;
    }
  }
  __syncthreads();
  if (t < BM) {
    // stats layout [vb][m] for coalesced combine
    size_t o = (size_t)vb * M_ROWS + mbase + t;
    smax[o] = fmaxf(redmax[t * 2], redmax[t * 2 + 1]);
    ssum[o] = redsum[t * 2] + redsum[t * 2 + 1];
  }
  #pragma unroll
  for (int k = 0; k < 4; ++k) {
    #pragma unroll
    for (int j = 0; j < 4; ++j) {
      #pragma unroll
      for (int r = 0; r < 4; ++r) {
        int grow = mbase + rowb + k * 16 + quad * 4 + r;
        int gcol = vbase + wv * 64 + j * 16 + lrow;
        __builtin_nontemporal_store(acc[k][j][r], out + (size_t)grow * V_DIM + gcol);
      }
    }
  }
}

// combine stage 1: 25 vb-segments x 2048 rows -> partial (max, sum-at-local-max)
__global__ __launch_bounds__(256) void gdecode_combine1(
    const float* __restrict__ smax, const float* __restrict__ ssum,
    float* __restrict__ pmax, float* __restrict__ psum)
{
  const int seg = blockIdx.x % NSEG;              // grid = 25 * 8 = 200
  const int m   = (blockIdx.x / NSEG) * 256 + threadIdx.x;
  float Mv = -3.4e38f;
  #pragma unroll
  for (int j = 0; j < SEGV; ++j)
    Mv = fmaxf(Mv, smax[(size_t)(seg * SEGV + j) * M_ROWS + m]);
  float S = 0.f;
  #pragma unroll
  for (int j = 0; j < SEGV; ++j) {
    const size_t o = (size_t)(seg * SEGV + j) * M_ROWS + m;
    S += ssum[o] * __expf(smax[o] - Mv);
  }
  pmax[(size_t)seg * M_ROWS + m] = Mv;
  psum[(size_t)seg * M_ROWS + m] = S;
}

// streaming normalize (combine2 folded in: row stats are block-uniform -> scalar loads):
// out = exp(l - M) / S; 4 chunks of 8000 floats per row
__global__ __launch_bounds__(256) void gdecode_norm(
    float* __restrict__ out, const float* __restrict__ pmax, const float* __restrict__ psum)
{
  const int m = blockIdx.x >> 2;
  const int c = blockIdx.x & 3;
  float Mv = -3.4e38f;
  #pragma unroll
  for (int s = 0; s < NSEG; ++s) Mv = fmaxf(Mv, pmax[(size_t)s * M_ROWS + m]);
  float S = 0.f;
  #pragma unroll
  for (int s = 0; s < NSEG; ++s)
    S += psum[(size_t)s * M_ROWS + m] * __expf(pmax[(size_t)s * M_ROWS + m] - Mv);
  const float Iv = 1.f / S;

  f32x4* row = (f32x4*)(out + (size_t)m * V_DIM + c * 8000);
  for (int i = threadIdx.x; i < 2000; i += 256) {
    f32x4 x = __builtin_nontemporal_load(row + i);
    f32x4 y;
    y[0] = __expf(x[0] - Mv) * Iv;
    y[1] = __expf(x[1] - Mv) * Iv;
    y[2] = __expf(x[2] - Mv) * Iv;
    y[3] = __expf(x[3] - Mv) * Iv;
    __builtin_nontemporal_store(y, row + i);
  }
}

// ------------------------------------------------------------------
// fallback path (previous verified kernel, unchanged)
// ------------------------------------------------------------------

__global__ __launch_bounds__(256, 2) void gdecode_gemm_fb(
    const float* __restrict__ phi, const float* __restrict__ psi,
    const int* __restrict__ perm, const int pstride,
    float* __restrict__ out, float* __restrict__ smax, float* __restrict__ ssum)
{
  __shared__ __align__(16) _Float16 lds[3 * BM * LDS_ROW];
  _Float16* sAhi = lds;
  _Float16* sAlo = lds + BM * LDS_ROW;
  _Float16* sB   = lds + 2 * BM * LDS_ROW;

  const int t     = threadIdx.x;
  const int vbase = blockIdx.x * BV;
  const int mbase = blockIdx.y * BM;

  const int kg = t & 7;
  const int r0 = t >> 3;

  const int wid  = t >> 6;
  const int lane = t & 63;
  const int wm   = wid & 1;
  const int wv   = wid >> 1;
  const int lrow = lane & 15;
  const int quad = lane >> 4;

  f32x4 acc[4][4] = {};

  for (int it = 0; it < 16; ++it) {
    const int cb  = it * BK;
    const int h   = cb >> 6;
    const int kin = cb & 63;

    float4 av[4], bv[4];
    #pragma unroll
    for (int i = 0; i < 4; ++i) {
      int m = r0 + i * 32;
      av[i] = *(const float4*)(phi + (size_t)(mbase + m) * C_DIM + cb + kg * 4);
    }
    #pragma unroll
    for (int i = 0; i < 4; ++i) {
      int v  = r0 + i * 32;
      int pr = perm[(size_t)(h * V_DIM + vbase + v) * pstride];
      bv[i]  = *(const float4*)(psi + (size_t)pr * K_DIM + kin + kg * 4);
    }

    __syncthreads();

    #pragma unroll
    for (int i = 0; i < 4; ++i) {
      int m = r0 + i * 32;
      float4 x = av[i];
      _Float16 h0 = (_Float16)x.x, h1 = (_Float16)x.y,
               h2 = (_Float16)x.z, h3 = (_Float16)x.w;
      f16x4 hi = {h0, h1, h2, h3};
      f16x4 lo = {(_Float16)(x.x - (float)h0), (_Float16)(x.y - (float)h1),
                  (_Float16)(x.z - (float)h2), (_Float16)(x.w - (float)h3)};
      *(f16x4*)(sAhi + m * LDS_ROW + kg * 4) = hi;
      *(f16x4*)(sAlo + m * LDS_ROW + kg * 4) = lo;
    }
    #pragma unroll
    for (int i = 0; i < 4; ++i) {
      int v = r0 + i * 32;
      float4 x = bv[i];
      f16x4 w = {(_Float16)x.x, (_Float16)x.y, (_Float16)x.z, (_Float16)x.w};
      *(f16x4*)(sB + v * LDS_ROW + kg * 4) = w;
    }

    __syncthreads();

    f16x8 ah[4], al[4], bf[4];
    #pragma unroll
    for (int i = 0; i < 4; ++i) {
      ah[i] = *(const f16x8*)(sAhi + (wm * 64 + i * 16 + lrow) * LDS_ROW + quad * 8);
      al[i] = *(const f16x8*)(sAlo + (wm * 64 + i * 16 + lrow) * LDS_ROW + quad * 8);
      bf[i] = *(const f16x8*)(sB   + (wv * 64 + i * 16 + lrow) * LDS_ROW + quad * 8);
    }
    #pragma unroll
    for (int i = 0; i < 4; ++i) {
      #pragma unroll
      for (int j = 0; j < 4; ++j) {
        acc[i][j] = __builtin_amdgcn_mfma_f32_16x16x32_f16(ah[i], bf[j], acc[i][j], 0, 0, 0);
        acc[i][j] = __builtin_amdgcn_mfma_f32_16x16x32_f16(al[i], bf[j], acc[i][j], 0, 0, 0);
      }
    }
  }

  __syncthreads();
  float* redmax = (float*)lds;
  float* redsum = redmax + 2 * BM;
  const int rowb = wm * 64;

  #pragma unroll
  for (int i = 0; i < 4; ++i) {
    #pragma unroll
    for (int r = 0; r < 4; ++r) {
      float v = fmaxf(fmaxf(acc[i][0][r], acc[i][1][r]),
                      fmaxf(acc[i][2][r], acc[i][3][r]));
      v = fmaxf(v, __shfl_xor(v, 1));
      v = fmaxf(v, __shfl_xor(v, 2));
      v = fmaxf(v, __shfl_xor(v, 4));
      v = fmaxf(v, __shfl_xor(v, 8));
      if (lrow == 0) redmax[(rowb + i * 16 + quad * 4 + r) * 2 + wv] = v;
    }
  }
  __syncthreads();
  float gmx[4][4];
  #pragma unroll
  for (int i = 0; i < 4; ++i) {
    #pragma unroll
    for (int r = 0; r < 4; ++r) {
      int row = rowb + i * 16 + quad * 4 + r;
      gmx[i][r] = fmaxf(redmax[row * 2], redmax[row * 2 + 1]);
    }
  }
  #pragma unroll
  for (int i = 0; i < 4; ++i) {
    #pragma unroll
    for (int r = 0; r < 4; ++r) {
      float s = __expf(acc[i][0][r] - gmx[i][r]) + __expf(acc[i][1][r] - gmx[i][r])
              + __expf(acc[i][2][r] - gmx[i][r]) + __expf(acc[i][3][r] - gmx[i][r]);
      s += __shfl_xor(s, 1);
      s += __shfl_xor(s, 2);
      s += __shfl_xor(s, 4);
      s += __shfl_xor(s, 8);
      if (lrow == 0) redsum[(rowb + i * 16 + quad * 4 + r) * 2 + wv] = s;
    }
  }
  __syncthreads();
  if (smax != nullptr && t < BM) {
    int row = t;
    size_t o = (size_t)(mbase + row) * NVBLK + blockIdx.x;
    smax[o] = fmaxf(redmax[row * 2], redmax[row * 2 + 1]);
    ssum[o] = redsum[row * 2] + redsum[row * 2 + 1];
  }
  #pragma unroll
  for (int i = 0; i < 4; ++i) {
    #pragma unroll
    for (int j = 0; j < 4; ++j) {
      #pragma unroll
      for (int r = 0; r < 4; ++r) {
        int grow = mbase + rowb + i * 16 + quad * 4 + r;
        int gcol = vbase + wv * 64 + j * 16 + lrow;
        out[(size_t)grow * V_DIM + gcol] = acc[i][j][r];
      }
    }
  }
}

__global__ __launch_bounds__(256) void gdecode_softmax_ws(
    float* __restrict__ out, const float* __restrict__ smax, const float* __restrict__ ssum)
{
  __shared__ float sbuf[4];
  const int m = blockIdx.x;
  const int t = threadIdx.x;
  const float* rm = smax + (size_t)m * NVBLK;
  const float* rs = ssum + (size_t)m * NVBLK;

  float lm = -3.4e38f;
  for (int i = t; i < NVBLK; i += 256) lm = fmaxf(lm, rm[i]);
  for (int d = 1; d < 64; d <<= 1) lm = fmaxf(lm, __shfl_xor(lm, d));
  if ((t & 63) == 0) sbuf[t >> 6] = lm;
  __syncthreads();
  const float M = fmaxf(fmaxf(sbuf[0], sbuf[1]), fmaxf(sbuf[2], sbuf[3]));
  __syncthreads();

  float ls = 0.f;
  for (int i = t; i < NVBLK; i += 256) ls += rs[i] * __expf(rm[i] - M);
  for (int d = 1; d < 64; d <<= 1) ls += __shfl_xor(ls, d);
  if ((t & 63) == 0) sbuf[t >> 6] = ls;
  __syncthreads();
  const float inv = 1.f / (sbuf[0] + sbuf[1] + sbuf[2] + sbuf[3]);

  float4* row = (float4*)(out + (size_t)m * V_DIM);
  for (int i = t; i < V_DIM / 4; i += 256) {
    float4 x = row[i];
    x.x = __expf(x.x - M) * inv;
    x.y = __expf(x.y - M) * inv;
    x.z = __expf(x.z - M) * inv;
    x.w = __expf(x.w - M) * inv;
    row[i] = x;
  }
}

__global__ __launch_bounds__(256) void gdecode_softmax_nows(float* __restrict__ out)
{
  __shared__ float sbuf[4];
  const int m = blockIdx.x;
  const int t = threadIdx.x;
  float4* row = (float4*)(out + (size_t)m * V_DIM);

  float lm = -3.4e38f;
  for (int i = t; i < V_DIM / 4; i += 256) {
    float4 x = row[i];
    lm = fmaxf(lm, fmaxf(fmaxf(x.x, x.y), fmaxf(x.z, x.w)));
  }
  for (int d = 1; d < 64; d <<= 1) lm = fmaxf(lm, __shfl_xor(lm, d));
  if ((t & 63) == 0) sbuf[t >> 6] = lm;
  __syncthreads();
  const float M = fmaxf(fmaxf(sbuf[0], sbuf[1]), fmaxf(sbuf[2], sbuf[3]));
  __syncthreads();

  float ls = 0.f;
  for (int i = t; i < V_DIM / 4; i += 256) {
    float4 x = row[i];
    ls += __expf(x.x - M) + __expf(x.y - M) + __expf(x.z - M) + __expf(x.w - M);
  }
  for (int d = 1; d < 64; d <<= 1) ls += __shfl_xor(ls, d);
  if ((t & 63) == 0) sbuf[t >> 6] = ls;
  __syncthreads();
  const float inv = 1.f / (sbuf[0] + sbuf[1] + sbuf[2] + sbuf[3]);

  for (int i = t; i < V_DIM / 4; i += 256) {
    float4 x = row[i];
    x.x = __expf(x.x - M) * inv;
    x.y = __expf(x.y - M) * inv;
    x.z = __expf(x.z - M) * inv;
    x.w = __expf(x.w - M) * inv;
    row[i] = x;
  }
}

// ------------------------------------------------------------------

extern "C" void kernel_launch(void* const* d_in, const int* in_sizes, int n_in,
                              void* d_out, int out_size, void* d_ws, size_t ws_size,
                              hipStream_t stream)
{
  const float* phi  = (const float*)d_in[0];   // [2048][512] fp32
  const float* psi  = (const float*)d_in[1];   // [32000][64] fp32
  const int*   perm = (const int*)d_in[2];     // [8][32000] (int64 guard below)
  const int pstride = (in_sizes[2] == 2 * G_DIM * V_DIM) ? 2 : 1;

  float* out = (float*)d_out;

  // fast-path workspace layout (bytes):
  //   AWS  f16 [16][16][2][4096 f16]  = 4,194,304
  //   BWS  f16 [16][250][4096 f16]    = 32,768,000
  //   smax f32 [250][2048]            = 2,048,000
  //   ssum f32 [250][2048]            = 2,048,000
  //   pmax f32 [25][2048], psum f32 [25][2048] = 2 x 204,800
  const size_t AWS_B  = (size_t)NMT * NKT * 2 * 4096 * 2;
  const size_t BWS_B  = (size_t)NKT * NVBLK * 4096 * 2;
  const size_t STAT_B = (size_t)NVBLK * M_ROWS * 4;
  const size_t PART_B = (size_t)NSEG * M_ROWS * 4;
  const size_t need_fast = AWS_B + BWS_B + 2 * STAT_B + 2 * PART_B;

  if (d_ws != nullptr && ws_size >= need_fast) {
    char* wp = (char*)d_ws;
    _Float16* aws = (_Float16*)wp;                 wp += AWS_B;
    _Float16* bws = (_Float16*)wp;                 wp += BWS_B;
    float* smax   = (float*)wp;                    wp += STAT_B;
    float* ssum   = (float*)wp;                    wp += STAT_B;
    float* pmax   = (float*)wp;                    wp += PART_B;
    float* psum   = (float*)wp;

    gdecode_prep_phi<<<(NMT * NKT * 2 * 512) / 256, 256, 0, stream>>>(phi, aws);
    gdecode_prep_psi<<<(NKT * NVBLK * 512) / 256, 256, 0, stream>>>(psi, perm, pstride, bws);

    gdecode_gemm2<<<4096, 256, 0, stream>>>(aws, bws, out, smax, ssum);

    gdecode_combine1<<<NSEG * (M_ROWS / 256), 256, 0, stream>>>(smax, ssum, pmax, psum);
    gdecode_norm<<<M_ROWS * 4, 256, 0, stream>>>(out, pmax, psum);
    return;
  }

  // fallback: previous verified path
  const size_t need_old = (size_t)M_ROWS * NVBLK * 2 * sizeof(float);
  const bool hasws = (d_ws != nullptr) && (ws_size >= need_old);
  float* smax = hasws ? (float*)d_ws : nullptr;
  float* ssum = hasws ? smax + (size_t)M_ROWS * NVBLK : nullptr;

  dim3 grid(NVBLK, M_ROWS / BM);
  gdecode_gemm_fb<<<grid, 256, 0, stream>>>(phi, psi, perm, pstride, out, smax, ssum);

  if (hasws)
    gdecode_softmax_ws<<<M_ROWS, 256, 0, stream>>>(out, smax, ssum);
  else
    gdecode_softmax_nows<<<M_ROWS, 256, 0, stream>>>(out);
}

// Round 5
// 537.398 us; speedup vs baseline: 1.0119x; 1.0119x over previous
//
#include <hip/hip_runtime.h>
#include <math.h>

// GDecode: logits[m,v] = sum_{h,k} phi[m, h*64+k] * psi[perm[h,v], k]; out = softmax_v(logits)
// M=2048 (B*N), C=512 (G*K), V=32000.
// Fast path (4 dispatches):
//   1) gdecode_prep   — merged: pre-gather psi->f16 BWS (row-major gather: 8 lanes consume one
//      256B psi row, emitting both k-halves) + pre-convert phi (hi/lo f16 Dekker) -> AWS.
//   2) gdecode_gemm2  — round-2-VERIFIED schedule: double-buffered global_load_lds staging,
//      issue-next-tile-before-compute, __syncthreads pipeline, XCD-chunked vb ownership
//      (each XCD's L2 holds one 4 MB BWS chunk). NT logit stores (protect L2 BWS chunks).
//   3) gdecode_combine1 — 25 vb-segments -> partial row stats.
//   4) gdecode_norm   — folds final combine (25 partials, block-uniform scalar loads) +
//      streaming normalize (regular loads, NT stores).
// Numerics identical to the verified kernel (same hi/lo split, same RNE psi cast, same MFMA
// accumulation order, same combine math) -> absmax unchanged.

#define M_ROWS 2048
#define V_DIM  32000
#define C_DIM  512
#define G_DIM  8
#define K_DIM  64
#define BM     128
#define BV     128
#define BK     32
#define NVBLK  (V_DIM / BV)   // 250
#define NMT    (M_ROWS / BM)  // 16
#define NKT    (C_DIM / BK)   // 16
#define NSEG   25             // combine1 vb segments
#define SEGV   (NVBLK / NSEG) // 10
#define LDSBUF 12288          // f16 elems per pipeline buffer: Ah(4096) | Al(4096) | B(4096)
#define PSI_BLKS 8000         // prep: 8 h * 1000 v-groups
#define PHI_BLKS 1024         // prep: 16*16*2*512 / 256
#define LDS_ROW 40            // fallback-path pad (old kernel)

typedef _Float16 f16x8 __attribute__((ext_vector_type(8)));
typedef _Float16 f16x4 __attribute__((ext_vector_type(4)));
typedef float    f32x4 __attribute__((ext_vector_type(4)));

// ------------------------------------------------------------------
// fast path
// ------------------------------------------------------------------

__device__ __forceinline__ void gl_lds16(const void* g, void* l) {
  __builtin_amdgcn_global_load_lds(
      (const __attribute__((address_space(1))) unsigned int*)g,
      (__attribute__((address_space(3))) unsigned int*)l, 16, 0, 0);
}

// Merged prep.
// Blocks [0, 8000): psi gather. block b: h = b/1000, vg = b%1000; thread t: v = vg*32 + (t>>3),
//   kq8 = t&7. Reads psi[perm[h][v]][kq8*8 .. +8] (8 consecutive lanes cover one 256B row ->
//   full-line random gather). Emits to BWS tile it = 2h + (kq8>>2), kq = kq8&3, r = v&127,
//   vb = v>>7 — byte-identical to the old kq-major prep.
// Blocks [8000, 9024): phi hi/lo. ga = (b-8000)*256 + t as before.
// AWS layout: [mt 16][it 16][half 2][kq 4][row 128][8 f16]
// BWS layout: [it 16][vb 250][kq 4][row 128][8 f16]
__global__ __launch_bounds__(256) void gdecode_prep(
    const float* __restrict__ phi, const float* __restrict__ psi,
    const int* __restrict__ perm, const int pstride,
    _Float16* __restrict__ aws, _Float16* __restrict__ bws)
{
  const int b = blockIdx.x;
  const int t = threadIdx.x;
  if (b < PSI_BLKS) {
    const int h   = b / 1000;
    const int vg  = b - h * 1000;
    const int v   = vg * 32 + (t >> 3);
    const int kq8 = t & 7;
    const int pr  = perm[(size_t)(h * V_DIM + v) * pstride];
    const float4 x0 = *(const float4*)(psi + (size_t)pr * K_DIM + kq8 * 8);
    const float4 x1 = *(const float4*)(psi + (size_t)pr * K_DIM + kq8 * 8 + 4);
    f16x8 o = {(_Float16)x0.x, (_Float16)x0.y, (_Float16)x0.z, (_Float16)x0.w,
               (_Float16)x1.x, (_Float16)x1.y, (_Float16)x1.z, (_Float16)x1.w};
    const int it = 2 * h + (kq8 >> 2);
    const int kq = kq8 & 3;
    const int vb = v >> 7;
    const int r  = v & 127;
    *(f16x8*)(bws + ((((size_t)it * NVBLK + vb) * 4 + kq) * 128 + r) * 8) = o;
  } else {
    const int ga   = (b - PSI_BLKS) * 256 + t;        // [0, 16*16*2*512)
    const int g    = ga & 511;
    const int half = (ga >> 9) & 1;
    const int tile = ga >> 10;                        // mt*16 + it
    const int kq = g >> 7, r = g & 127;
    const int m  = (tile >> 4) * BM + r;
    const int k  = (tile & 15) * BK + kq * 8;
    const float4 x0 = *(const float4*)(phi + (size_t)m * C_DIM + k);
    const float4 x1 = *(const float4*)(phi + (size_t)m * C_DIM + k + 4);
    const float xs[8] = {x0.x, x0.y, x0.z, x0.w, x1.x, x1.y, x1.z, x1.w};
    f16x8 o;
    #pragma unroll
    for (int j = 0; j < 8; ++j) {
      _Float16 hi = (_Float16)xs[j];
      o[j] = half ? (_Float16)(xs[j] - (float)hi) : hi;
    }
    *(f16x8*)(aws + (size_t)ga * 8) = o;
  }
}

__global__ __launch_bounds__(256, 4) void gdecode_gemm2(
    const _Float16* __restrict__ aws, const _Float16* __restrict__ bws,
    float* __restrict__ out, float* __restrict__ smax, float* __restrict__ ssum)
{
  __shared__ __align__(16) _Float16 lds[2 * LDSBUF];   // 48 KiB: double-buffered Ah|Al|B

  // XCD-chunked swizzle: grid = 4096, b%8 = XCD, each XCD owns vb chunk [xcd*32, +32)
  // (4 MB of BWS = one L2), sweeps mt with vb-inner order for A-tile sharing.
  const int b   = blockIdx.x;
  const int xcd = b & 7;
  const int i   = b >> 3;            // 0..511
  const int mt  = i >> 5;            // 0..15  (vb-inner, mt-outer within XCD)
  const int vb  = xcd * 32 + (i & 31);
  if (vb >= NVBLK) return;           // 96 pad blocks (return before any barrier)

  const int vbase = vb * BV;
  const int mbase = mt * BM;

  const int t    = threadIdx.x;
  const int wid  = t >> 6;
  const int lane = t & 63;
  const int wm   = wid & 1;
  const int wv   = wid >> 1;
  const int lrow = lane & 15;
  const int quad = lane >> 4;

  const _Float16* gA = aws + (size_t)mt * NKT * 2 * 4096;
  const _Float16* gB = bws + (size_t)vb * 4096;

  // stage K-step `it` into pipeline buffer dst (6 x 16B-per-lane DMA, linear layout)
  auto STAGE = [&](int it, _Float16* dst) {
    const _Float16* ga = gA + (size_t)it * 2 * 4096;        // hi tile; lo at +4096
    const _Float16* gb = gB + (size_t)it * NVBLK * 4096;
    gl_lds16(ga + (size_t)t * 8,          dst + t * 8);
    gl_lds16(ga + 2048 + (size_t)t * 8,   dst + 2048 + t * 8);
    gl_lds16(ga + 4096 + (size_t)t * 8,   dst + 4096 + t * 8);
    gl_lds16(ga + 6144 + (size_t)t * 8,   dst + 6144 + t * 8);
    gl_lds16(gb + (size_t)t * 8,          dst + 8192 + t * 8);
    gl_lds16(gb + 2048 + (size_t)t * 8,   dst + 8192 + 2048 + t * 8);
  };

  f32x4 acc[4][4] = {};

  STAGE(0, lds);
  __syncthreads();                       // tile 0 visible

  for (int it = 0; it < 16; ++it) {
    _Float16* cur = lds + (it & 1) * LDSBUF;
    if (it < 15) STAGE(it + 1, lds + ((it & 1) ^ 1) * LDSBUF);  // issue BEFORE compute

    const _Float16* sAh = cur;
    const _Float16* sAl = cur + 4096;
    const _Float16* sB  = cur + 8192;

    f16x8 ah[4], al[4], bf[4];
    #pragma unroll
    for (int k = 0; k < 4; ++k) {
      const int ra = quad * 1024 + (wm * 64 + k * 16 + lrow) * 8;
      const int rb = quad * 1024 + (wv * 64 + k * 16 + lrow) * 8;
      ah[k] = *(const f16x8*)(sAh + ra);
      al[k] = *(const f16x8*)(sAl + ra);
      bf[k] = *(const f16x8*)(sB + rb);
    }
    #pragma unroll
    for (int k = 0; k < 4; ++k) {
      #pragma unroll
      for (int j = 0; j < 4; ++j) {
        acc[k][j] = __builtin_amdgcn_mfma_f32_16x16x32_f16(ah[k], bf[j], acc[k][j], 0, 0, 0);
        acc[k][j] = __builtin_amdgcn_mfma_f32_16x16x32_f16(al[k], bf[j], acc[k][j], 0, 0, 0);
      }
    }
    __syncthreads();   // drains next-tile DMA (hidden under the MFMAs above) + guards LDS reuse
  }

  // ---- epilogue: per-(row, vtile) stats + raw logit store (nontemporal) ----
  float* redmax = (float*)lds;        // [BM][2]
  float* redsum = redmax + 2 * BM;    // [BM][2]
  const int rowb = wm * 64;

  #pragma unroll
  for (int k = 0; k < 4; ++k) {
    #pragma unroll
    for (int r = 0; r < 4; ++r) {
      float v = fmaxf(fmaxf(acc[k][0][r], acc[k][1][r]),
                      fmaxf(acc[k][2][r], acc[k][3][r]));
      v = fmaxf(v, __shfl_xor(v, 1));
      v = fmaxf(v, __shfl_xor(v, 2));
      v = fmaxf(v, __shfl_xor(v, 4));
      v = fmaxf(v, __shfl_xor(v, 8));
      if (lrow == 0) redmax[(rowb + k * 16 + quad * 4 + r) * 2 + wv] = v;
    }
  }
  __syncthreads();
  float gmx[4][4];
  #pragma unroll
  for (int k = 0; k < 4; ++k) {
    #pragma unroll
    for (int r = 0; r < 4; ++r) {
      int row = rowb + k * 16 + quad * 4 + r;
      gmx[k][r] = fmaxf(redmax[row * 2], redmax[row * 2 + 1]);
    }
  }
  #pragma unroll
  for (int k = 0; k < 4; ++k) {
    #pragma unroll
    for (int r = 0; r < 4; ++r) {
      float s = __expf(acc[k][0][r] - gmx[k][r]) + __expf(acc[k][1][r] - gmx[k][r])
              + __expf(acc[k][2][r] - gmx[k][r]) + __expf(acc[k][3][r] - gmx[k][r]);
      s += __shfl_xor(s, 1);
      s += __shfl_xor(s, 2);
      s += __shfl_xor(s, 4);
      s += __shfl_xor(s, 8);
      if (lrow == 0) redsum[(rowb + k * 16 + quad * 4 + r) * 2 + wv] = s;
    }
  }
  __syncthreads();
  if (t < BM) {
    // stats layout [vb][m] for coalesced combine
    size_t o = (size_t)vb * M_ROWS + mbase + t;
    smax[o] = fmaxf(redmax[t * 2], redmax[t * 2 + 1]);
    ssum[o] = redsum[t * 2] + redsum[t * 2 + 1];
  }
  #pragma unroll
  for (int k = 0; k < 4; ++k) {
    #pragma unroll
    for (int j = 0; j < 4; ++j) {
      #pragma unroll
      for (int r = 0; r < 4; ++r) {
        int grow = mbase + rowb + k * 16 + quad * 4 + r;
        int gcol = vbase + wv * 64 + j * 16 + lrow;
        __builtin_nontemporal_store(acc[k][j][r], out + (size_t)grow * V_DIM + gcol);
      }
    }
  }
}

// combine stage 1: 25 vb-segments x 2048 rows -> partial (max, sum-at-local-max)
__global__ __launch_bounds__(256) void gdecode_combine1(
    const float* __restrict__ smax, const float* __restrict__ ssum,
    float* __restrict__ pmax, float* __restrict__ psum)
{
  const int seg = blockIdx.x % NSEG;              // grid = 25 * 8 = 200
  const int m   = (blockIdx.x / NSEG) * 256 + threadIdx.x;
  float Mv = -3.4e38f;
  #pragma unroll
  for (int j = 0; j < SEGV; ++j)
    Mv = fmaxf(Mv, smax[(size_t)(seg * SEGV + j) * M_ROWS + m]);
  float S = 0.f;
  #pragma unroll
  for (int j = 0; j < SEGV; ++j) {
    const size_t o = (size_t)(seg * SEGV + j) * M_ROWS + m;
    S += ssum[o] * __expf(smax[o] - Mv);
  }
  pmax[(size_t)seg * M_ROWS + m] = Mv;
  psum[(size_t)seg * M_ROWS + m] = S;
}

// streaming normalize (final combine folded in: row stats are block-uniform -> scalar loads):
// out = exp(l - M) / S; 4 chunks of 8000 floats per row. Regular loads (LLC hits possible),
// NT stores.
__global__ __launch_bounds__(256) void gdecode_norm(
    float* __restrict__ out, const float* __restrict__ pmax, const float* __restrict__ psum)
{
  const int m = blockIdx.x >> 2;
  const int c = blockIdx.x & 3;
  float Mv = -3.4e38f;
  #pragma unroll
  for (int s = 0; s < NSEG; ++s) Mv = fmaxf(Mv, pmax[(size_t)s * M_ROWS + m]);
  float S = 0.f;
  #pragma unroll
  for (int s = 0; s < NSEG; ++s)
    S += psum[(size_t)s * M_ROWS + m] * __expf(pmax[(size_t)s * M_ROWS + m] - Mv);
  const float Iv = 1.f / S;

  f32x4* row = (f32x4*)(out + (size_t)m * V_DIM + c * 8000);
  for (int i = threadIdx.x; i < 2000; i += 256) {
    f32x4 x = row[i];
    f32x4 y;
    y[0] = __expf(x[0] - Mv) * Iv;
    y[1] = __expf(x[1] - Mv) * Iv;
    y[2] = __expf(x[2] - Mv) * Iv;
    y[3] = __expf(x[3] - Mv) * Iv;
    __builtin_nontemporal_store(y, row + i);
  }
}

// ------------------------------------------------------------------
// fallback path (previous verified kernel, unchanged)
// ------------------------------------------------------------------

__global__ __launch_bounds__(256, 2) void gdecode_gemm_fb(
    const float* __restrict__ phi, const float* __restrict__ psi,
    const int* __restrict__ perm, const int pstride,
    float* __restrict__ out, float* __restrict__ smax, float* __restrict__ ssum)
{
  __shared__ __align__(16) _Float16 lds[3 * BM * LDS_ROW];
  _Float16* sAhi = lds;
  _Float16* sAlo = lds + BM * LDS_ROW;
  _Float16* sB   = lds + 2 * BM * LDS_ROW;

  const int t     = threadIdx.x;
  const int vbase = blockIdx.x * BV;
  const int mbase = blockIdx.y * BM;

  const int kg = t & 7;
  const int r0 = t >> 3;

  const int wid  = t >> 6;
  const int lane = t & 63;
  const int wm   = wid & 1;
  const int wv   = wid >> 1;
  const int lrow = lane & 15;
  const int quad = lane >> 4;

  f32x4 acc[4][4] = {};

  for (int it = 0; it < 16; ++it) {
    const int cb  = it * BK;
    const int h   = cb >> 6;
    const int kin = cb & 63;

    float4 av[4], bv[4];
    #pragma unroll
    for (int i = 0; i < 4; ++i) {
      int m = r0 + i * 32;
      av[i] = *(const float4*)(phi + (size_t)(mbase + m) * C_DIM + cb + kg * 4);
    }
    #pragma unroll
    for (int i = 0; i < 4; ++i) {
      int v  = r0 + i * 32;
      int pr = perm[(size_t)(h * V_DIM + vbase + v) * pstride];
      bv[i]  = *(const float4*)(psi + (size_t)pr * K_DIM + kin + kg * 4);
    }

    __syncthreads();

    #pragma unroll
    for (int i = 0; i < 4; ++i) {
      int m = r0 + i * 32;
      float4 x = av[i];
      _Float16 h0 = (_Float16)x.x, h1 = (_Float16)x.y,
               h2 = (_Float16)x.z, h3 = (_Float16)x.w;
      f16x4 hi = {h0, h1, h2, h3};
      f16x4 lo = {(_Float16)(x.x - (float)h0), (_Float16)(x.y - (float)h1),
                  (_Float16)(x.z - (float)h2), (_Float16)(x.w - (float)h3)};
      *(f16x4*)(sAhi + m * LDS_ROW + kg * 4) = hi;
      *(f16x4*)(sAlo + m * LDS_ROW + kg * 4) = lo;
    }
    #pragma unroll
    for (int i = 0; i < 4; ++i) {
      int v = r0 + i * 32;
      float4 x = bv[i];
      f16x4 w = {(_Float16)x.x, (_Float16)x.y, (_Float16)x.z, (_Float16)x.w};
      *(f16x4*)(sB + v * LDS_ROW + kg * 4) = w;
    }

    __syncthreads();

    f16x8 ah[4], al[4], bf[4];
    #pragma unroll
    for (int i = 0; i < 4; ++i) {
      ah[i] = *(const f16x8*)(sAhi + (wm * 64 + i * 16 + lrow) * LDS_ROW + quad * 8);
      al[i] = *(const f16x8*)(sAlo + (wm * 64 + i * 16 + lrow) * LDS_ROW + quad * 8);
      bf[i] = *(const f16x8*)(sB   + (wv * 64 + i * 16 + lrow) * LDS_ROW + quad * 8);
    }
    #pragma unroll
    for (int i = 0; i < 4; ++i) {
      #pragma unroll
      for (int j = 0; j < 4; ++j) {
        acc[i][j] = __builtin_amdgcn_mfma_f32_16x16x32_f16(ah[i], bf[j], acc[i][j], 0, 0, 0);
        acc[i][j] = __builtin_amdgcn_mfma_f32_16x16x32_f16(al[i], bf[j], acc[i][j], 0, 0, 0);
      }
    }
  }

  __syncthreads();
  float* redmax = (float*)lds;
  float* redsum = redmax + 2 * BM;
  const int rowb = wm * 64;

  #pragma unroll
  for (int i = 0; i < 4; ++i) {
    #pragma unroll
    for (int r = 0; r < 4; ++r) {
      float v = fmaxf(fmaxf(acc[i][0][r], acc[i][1][r]),
                      fmaxf(acc[i][2][r], acc[i][3][r]));
      v = fmaxf(v, __shfl_xor(v, 1));
      v = fmaxf(v, __shfl_xor(v, 2));
      v = fmaxf(v, __shfl_xor(v, 4));
      v = fmaxf(v, __shfl_xor(v, 8));
      if (lrow == 0) redmax[(rowb + i * 16 + quad * 4 + r) * 2 + wv] = v;
    }
  }
  __syncthreads();
  float gmx[4][4];
  #pragma unroll
  for (int i = 0; i < 4; ++i) {
    #pragma unroll
    for (int r = 0; r < 4; ++r) {
      int row = rowb + i * 16 + quad * 4 + r;
      gmx[i][r] = fmaxf(redmax[row * 2], redmax[row * 2 + 1]);
    }
  }
  #pragma unroll
  for (int i = 0; i < 4; ++i) {
    #pragma unroll
    for (int r = 0; r < 4; ++r) {
      float s = __expf(acc[i][0][r] - gmx[i][r]) + __expf(acc[i][1][r] - gmx[i][r])
              + __expf(acc[i][2][r] - gmx[i][r]) + __expf(acc[i][3][r] - gmx[i][r]);
      s += __shfl_xor(s, 1);
      s += __shfl_xor(s, 2);
      s += __shfl_xor(s, 4);
      s += __shfl_xor(s, 8);
      if (lrow == 0) redsum[(rowb + i * 16 + quad * 4 + r) * 2 + wv] = s;
    }
  }
  __syncthreads();
  if (smax != nullptr && t < BM) {
    int row = t;
    size_t o = (size_t)(mbase + row) * NVBLK + blockIdx.x;
    smax[o] = fmaxf(redmax[row * 2], redmax[row * 2 + 1]);
    ssum[o] = redsum[row * 2] + redsum[row * 2 + 1];
  }
  #pragma unroll
  for (int i = 0; i < 4; ++i) {
    #pragma unroll
    for (int j = 0; j < 4; ++j) {
      #pragma unroll
      for (int r = 0; r < 4; ++r) {
        int grow = mbase + rowb + i * 16 + quad * 4 + r;
        int gcol = vbase + wv * 64 + j * 16 + lrow;
        out[(size_t)grow * V_DIM + gcol] = acc[i][j][r];
      }
    }
  }
}

__global__ __launch_bounds__(256) void gdecode_softmax_ws(
    float* __restrict__ out, const float* __restrict__ smax, const float* __restrict__ ssum)
{
  __shared__ float sbuf[4];
  const int m = blockIdx.x;
  const int t = threadIdx.x;
  const float* rm = smax + (size_t)m * NVBLK;
  const float* rs = ssum + (size_t)m * NVBLK;

  float lm = -3.4e38f;
  for (int i = t; i < NVBLK; i += 256) lm = fmaxf(lm, rm[i]);
  for (int d = 1; d < 64; d <<= 1) lm = fmaxf(lm, __shfl_xor(lm, d));
  if ((t & 63) == 0) sbuf[t >> 6] = lm;
  __syncthreads();
  const float M = fmaxf(fmaxf(sbuf[0], sbuf[1]), fmaxf(sbuf[2], sbuf[3]));
  __syncthreads();

  float ls = 0.f;
  for (int i = t; i < NVBLK; i += 256) ls += rs[i] * __expf(rm[i] - M);
  for (int d = 1; d < 64; d <<= 1) ls += __shfl_xor(ls, d);
  if ((t & 63) == 0) sbuf[t >> 6] = ls;
  __syncthreads();
  const float inv = 1.f / (sbuf[0] + sbuf[1] + sbuf[2] + sbuf[3]);

  float4* row = (float4*)(out + (size_t)m * V_DIM);
  for (int i = t; i < V_DIM / 4; i += 256) {
    float4 x = row[i];
    x.x = __expf(x.x - M) * inv;
    x.y = __expf(x.y - M) * inv;
    x.z = __expf(x.z - M) * inv;
    x.w = __expf(x.w - M) * inv;
    row[i] = x;
  }
}

__global__ __launch_bounds__(256) void gdecode_softmax_nows(float* __restrict__ out)
{
  __shared__ float sbuf[4];
  const int m = blockIdx.x;
  const int t = threadIdx.x;
  float4* row = (float4*)(out + (size_t)m * V_DIM);

  float lm = -3.4e38f;
  for (int i = t; i < V_DIM / 4; i += 256) {
    float4 x = row[i];
    lm = fmaxf(lm, fmaxf(fmaxf(x.x, x.y), fmaxf(x.z, x.w)));
  }
  for (int d = 1; d < 64; d <<= 1) lm = fmaxf(lm, __shfl_xor(lm, d));
  if ((t & 63) == 0) sbuf[t >> 6] = lm;
  __syncthreads();
  const float M = fmaxf(fmaxf(sbuf[0], sbuf[1]), fmaxf(sbuf[2], sbuf[3]));
  __syncthreads();

  float ls = 0.f;
  for (int i = t; i < V_DIM / 4; i += 256) {
    float4 x = row[i];
    ls += __expf(x.x - M) + __expf(x.y - M) + __expf(x.z - M) + __expf(x.w - M);
  }
  for (int d = 1; d < 64; d <<= 1) ls += __shfl_xor(ls, d);
  if ((t & 63) == 0) sbuf[t >> 6] = ls;
  __syncthreads();
  const float inv = 1.f / (sbuf[0] + sbuf[1] + sbuf[2] + sbuf[3]);

  for (int i = t; i < V_DIM / 4; i += 256) {
    float4 x = row[i];
    x.x = __expf(x.x - M) * inv;
    x.y = __expf(x.y - M) * inv;
    x.z = __expf(x.z - M) * inv;
    x.w = __expf(x.w - M) * inv;
    row[i] = x;
  }
}

// ------------------------------------------------------------------

extern "C" void kernel_launch(void* const* d_in, const int* in_sizes, int n_in,
                              void* d_out, int out_size, void* d_ws, size_t ws_size,
                              hipStream_t stream)
{
  const float* phi  = (const float*)d_in[0];   // [2048][512] fp32
  const float* psi  = (const float*)d_in[1];   // [32000][64] fp32
  const int*   perm = (const int*)d_in[2];     // [8][32000] (int64 guard below)
  const int pstride = (in_sizes[2] == 2 * G_DIM * V_DIM) ? 2 : 1;

  float* out = (float*)d_out;

  // fast-path workspace layout (bytes):
  //   AWS  f16 [16][16][2][4096 f16]  = 4,194,304
  //   BWS  f16 [16][250][4096 f16]    = 32,768,000
  //   smax f32 [250][2048]            = 2,048,000
  //   ssum f32 [250][2048]            = 2,048,000
  //   pmax f32 [25][2048], psum f32 [25][2048] = 2 x 204,800
  const size_t AWS_B  = (size_t)NMT * NKT * 2 * 4096 * 2;
  const size_t BWS_B  = (size_t)NKT * NVBLK * 4096 * 2;
  const size_t STAT_B = (size_t)NVBLK * M_ROWS * 4;
  const size_t PART_B = (size_t)NSEG * M_ROWS * 4;
  const size_t need_fast = AWS_B + BWS_B + 2 * STAT_B + 2 * PART_B;

  if (d_ws != nullptr && ws_size >= need_fast) {
    char* wp = (char*)d_ws;
    _Float16* aws = (_Float16*)wp;                 wp += AWS_B;
    _Float16* bws = (_Float16*)wp;                 wp += BWS_B;
    float* smax   = (float*)wp;                    wp += STAT_B;
    float* ssum   = (float*)wp;                    wp += STAT_B;
    float* pmax   = (float*)wp;                    wp += PART_B;
    float* psum   = (float*)wp;

    gdecode_prep<<<PSI_BLKS + PHI_BLKS, 256, 0, stream>>>(phi, psi, perm, pstride, aws, bws);

    gdecode_gemm2<<<4096, 256, 0, stream>>>(aws, bws, out, smax, ssum);

    gdecode_combine1<<<NSEG * (M_ROWS / 256), 256, 0, stream>>>(smax, ssum, pmax, psum);
    gdecode_norm<<<M_ROWS * 4, 256, 0, stream>>>(out, pmax, psum);
    return;
  }

  // fallback: previous verified path
  const size_t need_old = (size_t)M_ROWS * NVBLK * 2 * sizeof(float);
  const bool hasws = (d_ws != nullptr) && (ws_size >= need_old);
  float* smax = hasws ? (float*)d_ws : nullptr;
  float* ssum = hasws ? smax + (size_t)M_ROWS * NVBLK : nullptr;

  dim3 grid(NVBLK, M_ROWS / BM);
  gdecode_gemm_fb<<<grid, 256, 0, stream>>>(phi, psi, perm, pstride, out, smax, ssum);

  if (hasws)
    gdecode_softmax_ws<<<M_ROWS, 256, 0, stream>>>(out, smax, ssum);
  else
    gdecode_softmax_nows<<<M_ROWS, 256, 0, stream>>>(out);
}